// Round 16
// baseline (24.121 us; speedup 1.0000x reference)
//
#include <hip/hip_runtime.h>
#include <math.h>

#define NF 32
#define NE 64
#define NA 64
#define NP 496

typedef __attribute__((ext_vector_type(8))) _Float16 f16x8;
typedef __attribute__((ext_vector_type(4))) _Float16 f16x4;
typedef __attribute__((ext_vector_type(2))) __fp16   h16x2;
typedef __attribute__((ext_vector_type(4))) float    f32x4;

#define W1T_S 72
#define XT_S  40
#define WT_S  40

// R14 base (21.3us) + column-pair phase 1: lane nl owns cols c1=nl+1, c2=31-nl
// (32 slots), col vectors preloaded to registers (cndmask select), only the
// row read (2 ds_read_b128) remains per tile: phase-1 DS 64 -> 36 b128/wave.
__global__ __launch_bounds__(256, 4) void afm_fwd(
    const float* __restrict__ x,    // (B,32,64)
    const float* __restrict__ W1,   // (64,64)
    const float* __restrict__ b1,   // (64)
    const float* __restrict__ w2,   // (64,1)
    const float* __restrict__ b2,   // (1)
    float* __restrict__ out,        // (B,64)
    float* __restrict__ attn,       // (B,496)
    int B)
{
    const int tid   = threadIdx.x;
    const int lane  = tid & 63;
    const int wv    = tid >> 6;
    const int smp   = wv >> 1;
    const int sub   = wv & 1;
    const int nlane = lane & 15;
    const int g     = lane >> 4;

    __shared__ __align__(16) _Float16 W1t[64][W1T_S];      // 9216 B
    __shared__ __align__(16) _Float16 xh[2][8][NF][8];     // 8192 B
    __shared__ __align__(16) _Float16 xT[2][NE][XT_S];     // 10240 B
    __shared__ __align__(16) _Float16 Wt[2][NF][WT_S];     // 5120 B
    __shared__ float s_l[2][NP];                           // 3968 B
    __shared__ unsigned short s_rc[512];                   // 1024 B

    // ---- block-cooperative: W1 -> W1t (f16, transposed), pair table ----
    {
        const int e = tid & 63, a0 = (tid >> 6) << 4;
        const float* wr = W1 + e * NA + a0;
        #pragma unroll
        for (int i = 0; i < 4; ++i) {
            const float4 v = *(const float4*)(wr + 4 * i);
            W1t[a0 + 4*i + 0][e] = (_Float16)v.x;
            W1t[a0 + 4*i + 1][e] = (_Float16)v.y;
            W1t[a0 + 4*i + 2][e] = (_Float16)v.z;
            W1t[a0 + 4*i + 3][e] = (_Float16)v.w;
        }
    }
    for (int p = tid; p < 512; p += 256) {
        const int pp = (p < NP) ? p : NP - 1;
        const float sq = sqrtf((float)(3969 - 8 * pp));
        int r = (int)((63.0f - sq) * 0.5f);
        int st = (r * (63 - r)) >> 1;
        if (pp < st) { --r; st = (r * (63 - r)) >> 1; }
        else { const int st2 = ((r + 1) * (62 - r)) >> 1; if (pp >= st2) { ++r; st = st2; } }
        const int c = pp - st + r + 1;
        s_rc[p] = (unsigned short)(r | (c << 8));
    }

    int b = blockIdx.x * 2 + smp;
    if (b >= B) b = B - 1;

    // ---- zero Wt[smp] (ordering rides bar1+bar2) ----
    {
        unsigned int* wz = (unsigned int*)&Wt[smp][0][0];
        #pragma unroll
        for (int i = 0; i < 5; ++i) {
            const int idx = i * 64 + lane;
            if (idx < 320) wz[sub * 320 + idx] = 0u;
        }
    }

    // ---- stage x[b] halves -> xh (e-subtiled) and xT (transposed) ----
    const float* __restrict__ xb = x + (size_t)b * (NF * NE);
    {
        const int r  = sub * 16 + (lane >> 2);
        const int e0 = (lane & 3) << 4;
        #pragma unroll
        for (int i = 0; i < 4; ++i) {
            const int e = e0 + 4 * i;
            const float4 v = *(const float4*)(xb + r * NE + e);
            f16x4 hv = { (_Float16)v.x, (_Float16)v.y, (_Float16)v.z, (_Float16)v.w };
            *(f16x4*)&xh[smp][e >> 3][r][e & 7] = hv;
            xT[smp][e + 0][r] = hv[0];
            xT[smp][e + 1][r] = hv[1];
            xT[smp][e + 2][r] = hv[2];
            xT[smp][e + 3][r] = hv[3];
        }
    }
    __syncthreads();   // bar1

    // ---- W1 A-frags from LDS (8 x ds_read_b128) ----
    f16x8 w1f[2][4];
    #pragma unroll
    for (int s = 0; s < 2; ++s)
        #pragma unroll
        for (int mt = 0; mt < 4; ++mt)
            w1f[s][mt] = *(const f16x8*)&W1t[mt * 16 + nlane][s * 32 + g * 8];

    f32x4 b1q[4];
    h16x2 w2h[4][2];
    #pragma unroll
    for (int mt = 0; mt < 4; ++mt) {
        b1q[mt] = *(const f32x4*)(b1 + mt * 16 + g * 4);
        const f32x4 wq = *(const f32x4*)(w2 + mt * 16 + g * 4);
        w2h[mt][0] = (h16x2){ (__fp16)wq[0], (__fp16)wq[1] };
        w2h[mt][1] = (h16x2){ (__fp16)wq[2], (__fp16)wq[3] };
    }
    const float bias2 = b2[0];
    const h16x2 zz = { (__fp16)0.0f, (__fp16)0.0f };

    // ---- phase 1, column-pair scheme ----
    // lane nl: col c1 = nl+1 (slots 0..c1-1), col c2 = 31-nl (rest). nl=15:
    // c2 = 16 -> slots 16..31 duplicate slots 0..15 (same pair, same value:
    // benign). Wave sub covers slots s = 16*sub + t, t = 0..15.
    const int c1 = nlane + 1;
    const int c2 = (nlane < 15) ? (31 - nlane) : 16;

    const f16x8 xc1h0 = *(const f16x8*)&xh[smp][g][c1][0];
    const f16x8 xc1h1 = *(const f16x8*)&xh[smp][4 + g][c1][0];
    const f16x8 xc2h0 = *(const f16x8*)&xh[smp][g][c2][0];
    const f16x8 xc2h1 = *(const f16x8*)&xh[smp][4 + g][c2][0];

    // first row read (slot 16*sub)
    int s0 = 16 * sub;
    int r_cur = (s0 >= c1) ? (s0 - c1) : s0;
    f16x8 xr_h0 = *(const f16x8*)&xh[smp][g][r_cur][0];
    f16x8 xr_h1 = *(const f16x8*)&xh[smp][4 + g][r_cur][0];

    #pragma unroll
    for (int t = 0; t < 16; ++t) {
        const int s = 16 * sub + t;
        const bool second = (s >= c1);
        const int r = second ? (s - c1) : s;
        const int c = second ? c2 : c1;

        // prefetch next tile's row (address pure arithmetic)
        f16x8 xrn_h0, xrn_h1;
        if (t < 15) {
            const int sn = s + 1;
            const int rn = (sn >= c1) ? (sn - c1) : sn;
            xrn_h0 = *(const f16x8*)&xh[smp][g][rn][0];
            xrn_h1 = *(const f16x8*)&xh[smp][4 + g][rn][0];
        }

        const f16x8 xch0 = second ? xc2h0 : xc1h0;   // cndmask select, no DS
        const f16x8 xch1 = second ? xc2h1 : xc1h1;
        const f16x8 af0 = xr_h0 * xch0;
        const f16x8 af1 = xr_h1 * xch1;

        f32x4 acc[4];
        __builtin_amdgcn_s_setprio(1);
        #pragma unroll
        for (int mt = 0; mt < 4; ++mt)               // b1 folded into C-operand
            acc[mt] = __builtin_amdgcn_mfma_f32_16x16x32_f16(w1f[0][mt], af0, b1q[mt], 0, 0, 0);
        #pragma unroll
        for (int mt = 0; mt < 4; ++mt)
            acc[mt] = __builtin_amdgcn_mfma_f32_16x16x32_f16(w1f[1][mt], af1, acc[mt], 0, 0, 0);
        __builtin_amdgcn_s_setprio(0);

        // packed relu-dot: cvt_pkrtz -> pk_max -> fdot2 (f32 accumulate)
        float plA = 0.f, plB = 0.f;
        #pragma unroll
        for (int mt = 0; mt < 4; ++mt) {
            h16x2 h01 = __builtin_amdgcn_cvt_pkrtz(acc[mt][0], acc[mt][1]);
            h16x2 h23 = __builtin_amdgcn_cvt_pkrtz(acc[mt][2], acc[mt][3]);
            h01 = __builtin_elementwise_max(h01, zz);
            h23 = __builtin_elementwise_max(h23, zz);
            plA = __builtin_amdgcn_fdot2(h01, w2h[mt][0], plA, false);
            plB = __builtin_amdgcn_fdot2(h23, w2h[mt][1], plB, false);
        }
        float logit = plA + plB;
        logit += __shfl_xor(logit, 16);
        logit += __shfl_xor(logit, 32);

        // pair index p = r*(63-r)/2 + c - r - 1 (per lane)
        const int p = ((r * (63 - r)) >> 1) + c - r - 1;
        if (lane < 16) s_l[smp][p] = logit + bias2;

        xr_h0 = xrn_h0; xr_h1 = xrn_h1;
    }
    __syncthreads();   // bar2: all 496 logits of both samples in LDS

    // ---- softmax: full 496, duplicated per wave (deterministic) ----
    float lv[8], mx = -1e30f;
    #pragma unroll
    for (int k = 0; k < 8; ++k) {
        const int p = (k << 6) + lane;
        lv[k] = (p < NP) ? s_l[smp][p] : -1e30f;
        mx = fmaxf(mx, lv[k]);
    }
    #pragma unroll
    for (int off = 1; off < 64; off <<= 1) mx = fmaxf(mx, __shfl_xor(mx, off));

    float ev[8], se = 0.0f;
    #pragma unroll
    for (int k = 0; k < 8; ++k) {
        const int p = (k << 6) + lane;
        ev[k] = (p < NP) ? __expf(lv[k] - mx) : 0.0f;
        se += ev[k];
    }
    #pragma unroll
    for (int off = 1; off < 64; off <<= 1) se += __shfl_xor(se, off);
    const float inv = 1.0f / se;

    // ---- scatter this wave's half of the weights; write attn ----
    float* __restrict__ attn_b = attn + (size_t)b * NP;
    #pragma unroll
    for (int k = 0; k < 4; ++k) {
        const int kk = (sub << 2) + k;
        const int p = (kk << 6) + lane;
        if (p < NP) {
            const float w = ev[kk] * inv;
            attn_b[p] = w;
            const unsigned short rc = s_rc[p];
            const int r = rc & 255, c = rc >> 8;
            const _Float16 wh = (_Float16)w;
            Wt[smp][r][c] = wh;
            Wt[smp][c][r] = wh;
        }
    }
    __syncthreads();   // bar3: Wt complete

    // ---- phase 3 as GEMM: Y = Wt @ X; out = 0.5 * sum_r x*y ----
    f16x8 wa[2], xbf[2];
    #pragma unroll
    for (int mt = 0; mt < 2; ++mt)
        wa[mt] = *(const f16x8*)&Wt[smp][mt * 16 + nlane][g * 8];
    #pragma unroll
    for (int j = 0; j < 2; ++j) {
        const int nt = 2 * sub + j;
        xbf[j] = *(const f16x8*)&xT[smp][nt * 16 + nlane][g * 8];
    }

    f32x4 y[2][2];
    #pragma unroll
    for (int mt = 0; mt < 2; ++mt)
        #pragma unroll
        for (int j = 0; j < 2; ++j) {
            y[mt][j] = (f32x4)0.0f;
            y[mt][j] = __builtin_amdgcn_mfma_f32_16x16x32_f16(wa[mt], xbf[j], y[mt][j], 0, 0, 0);
        }

    float po[2] = {0.f, 0.f};
    #pragma unroll
    for (int j = 0; j < 2; ++j) {
        const int nt = 2 * sub + j;
        #pragma unroll
        for (int mt = 0; mt < 2; ++mt) {
            const f16x4 xv = *(const f16x4*)&xT[smp][nt * 16 + nlane][mt * 16 + g * 4];
            po[j] += (float)xv[0] * y[mt][j][0];
            po[j] += (float)xv[1] * y[mt][j][1];
            po[j] += (float)xv[2] * y[mt][j][2];
            po[j] += (float)xv[3] * y[mt][j][3];
        }
        po[j] += __shfl_xor(po[j], 16);
        po[j] += __shfl_xor(po[j], 32);
    }
    if (lane < 16) {
        float* __restrict__ ob = out + (size_t)b * NE;
        #pragma unroll
        for (int j = 0; j < 2; ++j)
            ob[(2 * sub + j) * 16 + lane] = 0.5f * po[j];
    }
}

extern "C" void kernel_launch(void* const* d_in, const int* in_sizes, int n_in,
                              void* d_out, int out_size, void* d_ws, size_t ws_size,
                              hipStream_t stream) {
    const float* x  = (const float*)d_in[0];
    const float* W1 = (const float*)d_in[1];
    const float* b1 = (const float*)d_in[2];
    const float* w2 = (const float*)d_in[3];
    const float* b2 = (const float*)d_in[4];

    const int B = in_sizes[0] / (NF * NE);             // 2048
    float* out_p  = (float*)d_out;                     // (B,1,64) flat
    float* attn_p = (float*)d_out + (size_t)B * NE;    // (B,496,1) flat

    afm_fwd<<<(B + 1) / 2, 256, 0, stream>>>(x, W1, b1, w2, b2, out_p, attn_p, B);
}

// Round 17
// 20.837 us; speedup vs baseline: 1.1576x; 1.1576x over previous
//
#include <hip/hip_runtime.h>
#include <math.h>

#define NF 32
#define NE 64
#define NA 64
#define NP 496

typedef __attribute__((ext_vector_type(8))) _Float16 f16x8;
typedef __attribute__((ext_vector_type(4))) _Float16 f16x4;
typedef __attribute__((ext_vector_type(2))) __fp16   h16x2;
typedef __attribute__((ext_vector_type(4))) float    f32x4;

#define W1T_S 72
#define XT_S  40
#define WT_S  40

// R14 base (21.3us, best) with staging DS-cut: W1t and xT staged via 4x4
// in-register transposes -> 4 ds_write_b64 instead of 16 ds_write_u16 each
// (-24 DS instr/wave net, no added VALU). Everything else identical to R14.
__global__ __launch_bounds__(256, 4) void afm_fwd(
    const float* __restrict__ x,    // (B,32,64)
    const float* __restrict__ W1,   // (64,64)
    const float* __restrict__ b1,   // (64)
    const float* __restrict__ w2,   // (64,1)
    const float* __restrict__ b2,   // (1)
    float* __restrict__ out,        // (B,64)
    float* __restrict__ attn,      // (B,496)
    int B)
{
    const int tid   = threadIdx.x;
    const int lane  = tid & 63;
    const int wv    = tid >> 6;
    const int smp   = wv >> 1;
    const int sub   = wv & 1;
    const int nlane = lane & 15;
    const int g     = lane >> 4;

    __shared__ __align__(16) _Float16 W1t[64][W1T_S];      // 9216 B
    __shared__ __align__(16) _Float16 xh[2][8][NF][8];     // 8192 B
    __shared__ __align__(16) _Float16 xT[2][NE][XT_S];     // 10240 B
    __shared__ __align__(16) _Float16 Wt[2][NF][WT_S];     // 5120 B
    __shared__ float s_l[2][NP];                           // 3968 B
    __shared__ unsigned short s_rc[512];                   // 1024 B

    // ---- W1 -> W1t via 4x4 register transpose (4 ds_write_b64/thread) ----
    {
        const int a0 = (tid & 15) << 2;        // a-block
        const int e0 = (tid >> 4) << 2;        // e-block
        float4 v[4];
        #pragma unroll
        for (int j = 0; j < 4; ++j)
            v[j] = *(const float4*)(W1 + (e0 + j) * NA + a0);
        #pragma unroll
        for (int i = 0; i < 4; ++i) {
            f16x4 hv = { (_Float16)((const float*)&v[0])[i],
                         (_Float16)((const float*)&v[1])[i],
                         (_Float16)((const float*)&v[2])[i],
                         (_Float16)((const float*)&v[3])[i] };
            *(f16x4*)&W1t[a0 + i][e0] = hv;    // W1t[a][e0..e0+3]
        }
    }
    for (int p = tid; p < 512; p += 256) {
        const int pp = (p < NP) ? p : NP - 1;
        const float sq = sqrtf((float)(3969 - 8 * pp));
        int r = (int)((63.0f - sq) * 0.5f);
        int st = (r * (63 - r)) >> 1;
        if (pp < st) { --r; st = (r * (63 - r)) >> 1; }
        else { const int st2 = ((r + 1) * (62 - r)) >> 1; if (pp >= st2) { ++r; st = st2; } }
        const int c = pp - st + r + 1;
        s_rc[p] = (unsigned short)(r | (c << 8));
    }

    int b = blockIdx.x * 2 + smp;
    if (b >= B) b = B - 1;

    // ---- zero Wt[smp] (ordering rides bar1+bar2) ----
    {
        unsigned int* wz = (unsigned int*)&Wt[smp][0][0];
        #pragma unroll
        for (int i = 0; i < 5; ++i) {
            const int idx = i * 64 + lane;
            if (idx < 320) wz[sub * 320 + idx] = 0u;
        }
    }

    // ---- stage x[b]: 4x4 blocks -> xh rows + xT cols (8 ds_write_b64) ----
    const float* __restrict__ xb = x + (size_t)b * (NF * NE);
    {
        const int r0 = sub * 16 + ((lane >> 4) << 2);
        const int e0 = (lane & 15) << 2;
        float4 v[4];
        #pragma unroll
        for (int i = 0; i < 4; ++i)
            v[i] = *(const float4*)(xb + (r0 + i) * NE + e0);
        #pragma unroll
        for (int i = 0; i < 4; ++i) {          // xh[e-subtile][row][e&7]
            f16x4 hv = { (_Float16)v[i].x, (_Float16)v[i].y,
                         (_Float16)v[i].z, (_Float16)v[i].w };
            *(f16x4*)&xh[smp][e0 >> 3][r0 + i][e0 & 7] = hv;
        }
        #pragma unroll
        for (int j = 0; j < 4; ++j) {          // xT[e][r0..r0+3] (transposed)
            f16x4 hv = { (_Float16)((const float*)&v[0])[j],
                         (_Float16)((const float*)&v[1])[j],
                         (_Float16)((const float*)&v[2])[j],
                         (_Float16)((const float*)&v[3])[j] };
            *(f16x4*)&xT[smp][e0 + j][r0] = hv;
        }
    }

    // ---- per-lane (r,c) for striped pairs p = 31*nlane + 16*sub + t ----
    int pr, pc;
    {
        const int p0 = 31 * nlane + 16 * sub;
        const float sq = sqrtf((float)(3969 - 8 * p0));
        int r = (int)((63.0f - sq) * 0.5f);
        int st = (r * (63 - r)) >> 1;
        if (p0 < st) { --r; st = (r * (63 - r)) >> 1; }
        else { const int st2 = ((r + 1) * (62 - r)) >> 1; if (p0 >= st2) { ++r; st = st2; } }
        pr = r;
        pc = p0 - st + r + 1;
    }
    __syncthreads();   // bar1

    // ---- W1 A-frags from LDS (8 x ds_read_b128) ----
    f16x8 w1f[2][4];
    #pragma unroll
    for (int s = 0; s < 2; ++s)
        #pragma unroll
        for (int mt = 0; mt < 4; ++mt)
            w1f[s][mt] = *(const f16x8*)&W1t[mt * 16 + nlane][s * 32 + g * 8];

    f32x4 b1q[4];
    h16x2 w2h[4][2];
    #pragma unroll
    for (int mt = 0; mt < 4; ++mt) {
        b1q[mt] = *(const f32x4*)(b1 + mt * 16 + g * 4);
        const f32x4 wq = *(const f32x4*)(w2 + mt * 16 + g * 4);
        w2h[mt][0] = (h16x2){ (__fp16)wq[0], (__fp16)wq[1] };
        w2h[mt][1] = (h16x2){ (__fp16)wq[2], (__fp16)wq[3] };
    }
    const float bias2 = b2[0];
    const h16x2 zz = { (__fp16)0.0f, (__fp16)0.0f };

    // ---- phase 1, software-pipelined (R14): prefetch t+1 before computing t ----
    f16x8 xr0c = *(const f16x8*)&xh[smp][g][pr][0];
    f16x8 xc0c = *(const f16x8*)&xh[smp][g][pc][0];
    f16x8 xr1c = *(const f16x8*)&xh[smp][4 + g][pr][0];
    f16x8 xc1c = *(const f16x8*)&xh[smp][4 + g][pc][0];

    #pragma unroll
    for (int t = 0; t < 16; ++t) {
        if (16 * sub + t < 31) {
            int npc = pc + 1;
            const int wrap = (npc >= 32) ? 1 : 0;
            const int npr = pr + wrap;
            npc = wrap ? (npr + 1) : npc;
            f16x8 xr0n, xc0n, xr1n, xc1n;
            if (16 * sub + t + 1 < 31) {
                xr0n = *(const f16x8*)&xh[smp][g][npr][0];
                xc0n = *(const f16x8*)&xh[smp][g][npc][0];
                xr1n = *(const f16x8*)&xh[smp][4 + g][npr][0];
                xc1n = *(const f16x8*)&xh[smp][4 + g][npc][0];
            }

            const f16x8 af0 = xr0c * xc0c;
            const f16x8 af1 = xr1c * xc1c;

            f32x4 acc[4];
            __builtin_amdgcn_s_setprio(1);
            #pragma unroll
            for (int mt = 0; mt < 4; ++mt)         // b1 folded into C-operand
                acc[mt] = __builtin_amdgcn_mfma_f32_16x16x32_f16(w1f[0][mt], af0, b1q[mt], 0, 0, 0);
            #pragma unroll
            for (int mt = 0; mt < 4; ++mt)
                acc[mt] = __builtin_amdgcn_mfma_f32_16x16x32_f16(w1f[1][mt], af1, acc[mt], 0, 0, 0);
            __builtin_amdgcn_s_setprio(0);

            float plA = 0.f, plB = 0.f;
            #pragma unroll
            for (int mt = 0; mt < 4; ++mt) {
                h16x2 h01 = __builtin_amdgcn_cvt_pkrtz(acc[mt][0], acc[mt][1]);
                h16x2 h23 = __builtin_amdgcn_cvt_pkrtz(acc[mt][2], acc[mt][3]);
                h01 = __builtin_elementwise_max(h01, zz);
                h23 = __builtin_elementwise_max(h23, zz);
                plA = __builtin_amdgcn_fdot2(h01, w2h[mt][0], plA, false);
                plB = __builtin_amdgcn_fdot2(h23, w2h[mt][1], plB, false);
            }
            float logit = plA + plB;
            logit += __shfl_xor(logit, 16);
            logit += __shfl_xor(logit, 32);
            if (lane < 16) s_l[smp][31 * lane + 16 * sub + t] = logit + bias2;

            pr = npr; pc = npc;
            xr0c = xr0n; xc0c = xc0n; xr1c = xr1n; xc1c = xc1n;
        }
    }
    __syncthreads();   // bar2: all 496 logits of both samples in LDS

    // ---- softmax: full 496, duplicated per wave (deterministic) ----
    float lv[8], mx = -1e30f;
    #pragma unroll
    for (int k = 0; k < 8; ++k) {
        const int p = (k << 6) + lane;
        lv[k] = (p < NP) ? s_l[smp][p] : -1e30f;
        mx = fmaxf(mx, lv[k]);
    }
    #pragma unroll
    for (int off = 1; off < 64; off <<= 1) mx = fmaxf(mx, __shfl_xor(mx, off));

    float ev[8], se = 0.0f;
    #pragma unroll
    for (int k = 0; k < 8; ++k) {
        const int p = (k << 6) + lane;
        ev[k] = (p < NP) ? __expf(lv[k] - mx) : 0.0f;
        se += ev[k];
    }
    #pragma unroll
    for (int off = 1; off < 64; off <<= 1) se += __shfl_xor(se, off);
    const float inv = 1.0f / se;

    // ---- scatter this wave's half of the weights; write attn ----
    float* __restrict__ attn_b = attn + (size_t)b * NP;
    #pragma unroll
    for (int k = 0; k < 4; ++k) {
        const int kk = (sub << 2) + k;
        const int p = (kk << 6) + lane;
        if (p < NP) {
            const float w = ev[kk] * inv;
            attn_b[p] = w;
            const unsigned short rc = s_rc[p];
            const int r = rc & 255, c = rc >> 8;
            const _Float16 wh = (_Float16)w;
            Wt[smp][r][c] = wh;
            Wt[smp][c][r] = wh;
        }
    }
    __syncthreads();   // bar3: Wt complete

    // ---- phase 3 as GEMM: Y = Wt @ X; out = 0.5 * sum_r x*y ----
    f16x8 wa[2], xbf[2];
    #pragma unroll
    for (int mt = 0; mt < 2; ++mt)
        wa[mt] = *(const f16x8*)&Wt[smp][mt * 16 + nlane][g * 8];
    #pragma unroll
    for (int j = 0; j < 2; ++j) {
        const int nt = 2 * sub + j;
        xbf[j] = *(const f16x8*)&xT[smp][nt * 16 + nlane][g * 8];
    }

    f32x4 y[2][2];
    #pragma unroll
    for (int mt = 0; mt < 2; ++mt)
        #pragma unroll
        for (int j = 0; j < 2; ++j) {
            y[mt][j] = (f32x4)0.0f;
            y[mt][j] = __builtin_amdgcn_mfma_f32_16x16x32_f16(wa[mt], xbf[j], y[mt][j], 0, 0, 0);
        }

    float po[2] = {0.f, 0.f};
    #pragma unroll
    for (int j = 0; j < 2; ++j) {
        const int nt = 2 * sub + j;
        #pragma unroll
        for (int mt = 0; mt < 2; ++mt) {
            const f16x4 xv = *(const f16x4*)&xT[smp][nt * 16 + nlane][mt * 16 + g * 4];
            po[j] += (float)xv[0] * y[mt][j][0];
            po[j] += (float)xv[1] * y[mt][j][1];
            po[j] += (float)xv[2] * y[mt][j][2];
            po[j] += (float)xv[3] * y[mt][j][3];
        }
        po[j] += __shfl_xor(po[j], 16);
        po[j] += __shfl_xor(po[j], 32);
    }
    if (lane < 16) {
        float* __restrict__ ob = out + (size_t)b * NE;
        #pragma unroll
        for (int j = 0; j < 2; ++j)
            ob[(2 * sub + j) * 16 + lane] = 0.5f * po[j];
    }
}

extern "C" void kernel_launch(void* const* d_in, const int* in_sizes, int n_in,
                              void* d_out, int out_size, void* d_ws, size_t ws_size,
                              hipStream_t stream) {
    const float* x  = (const float*)d_in[0];
    const float* W1 = (const float*)d_in[1];
    const float* b1 = (const float*)d_in[2];
    const float* w2 = (const float*)d_in[3];
    const float* b2 = (const float*)d_in[4];

    const int B = in_sizes[0] / (NF * NE);             // 2048
    float* out_p  = (float*)d_out;                     // (B,1,64) flat
    float* attn_p = (float*)d_out + (size_t)B * NE;    // (B,496,1) flat

    afm_fwd<<<(B + 1) / 2, 256, 0, stream>>>(x, W1, b1, w2, b2, out_p, attn_p, B);
}